// Round 6
// baseline (4455.940 us; speedup 1.0000x reference)
//
#include <hip/hip_runtime.h>
#include <math.h>

#define BB 2
#define LL 2048
#define DM 1024
#define NH 16
#define HD 64

__device__ __forceinline__ unsigned mono32(float f) {
    unsigned u = __float_as_uint(f);
    return (u & 0x80000000u) ? ~u : (u | 0x80000000u);
}

// ---------------------------------------------------------------------------
// 1024x1024 transpose: out[k][n] = in[n][k]
// ---------------------------------------------------------------------------
__global__ __launch_bounds__(256) void transpose1024(
    const float* __restrict__ in, float* __restrict__ out)
{
    __shared__ float t[32][33];
    const int bx = blockIdx.x * 32, by = blockIdx.y * 32;
    const int tx = threadIdx.x & 31, ty = threadIdx.x >> 5;
    for (int r = ty; r < 32; r += 8)
        t[r][tx] = in[(size_t)(by + r) * DM + bx + tx];
    __syncthreads();
    for (int r = ty; r < 32; r += 8)
        out[(size_t)(bx + r) * DM + by + tx] = t[tx][r];
}

// ---------------------------------------------------------------------------
// Bit-emulated f32 projection (numpy -> OpenBLAS sgemm, Zen/Haswell):
// K-panels per level3.c driver logic with GEMM_Q=384 on K=1024:
//   rem=1024 >= 2Q -> 384 ; rem=640 in (Q,2Q] -> 320 ; rem=320 -> 320
// => panels (384,320,320). Within a panel: one serial ascending-k FMA chain
// per C element (vfmadd231ps microkernel). C += panel in order, then +bias.
// Scatter to [B,H,L,D]. Wt is W transposed [k][n].
// ---------------------------------------------------------------------------
__global__ __launch_bounds__(256) void proj_emul(
    const float* __restrict__ x, const float* __restrict__ Wt,
    const float* __restrict__ bias, float* __restrict__ outp)
{
    __shared__ float xs[8][DM];   // 32 KB
    const int tid = threadIdx.x;
    const int n   = blockIdx.x * 256 + tid;
    const int m0  = blockIdx.y * 8;

    for (int i = tid; i < 8 * 256; i += 256) {
        const int r = i >> 8, c4 = (i & 255) << 2;
        *(float4*)&xs[r][c4] = *(const float4*)&x[(size_t)(m0 + r) * DM + c4];
    }
    __syncthreads();

    const int kbound[4] = {0, 384, 704, 1024};   // OpenBLAS Zen panel splits

    float S[8] = {0, 0, 0, 0, 0, 0, 0, 0};
#pragma unroll
    for (int p = 0; p < 3; p++) {
        float P[8] = {0, 0, 0, 0, 0, 0, 0, 0};
        for (int k = kbound[p]; k < kbound[p + 1]; k++) {
            const float w = Wt[(size_t)k * DM + n];
#pragma unroll
            for (int m = 0; m < 8; m++) P[m] = fmaf(xs[m][k], w, P[m]);
        }
#pragma unroll
        for (int m = 0; m < 8; m++) S[m] += P[m];   // C += panel (in order)
    }

    const int h = n / HD, d = n % HD;
#pragma unroll
    for (int m = 0; m < 8; m++) {
        const int mm = m0 + m;
        const int b = mm / LL, l = mm % LL;
        outp[(((size_t)b * NH + h) * LL + l) * HD + d] = S[m] + bias[n];
    }
}

// ---------------------------------------------------------------------------
// f32 GEMM for V (MODE 0 scatter) and output projection (MODE 1). Precision
// here is tolerance-covered — only speed matters.
// ---------------------------------------------------------------------------
template <int MODE>
__global__ __launch_bounds__(256) void gemm_f32(
    const float* __restrict__ A, const float* __restrict__ W,
    const float* __restrict__ bias, float* __restrict__ out,
    int M, int N, int K)
{
    __shared__ float As[16][64];
    __shared__ float Bs[16][64];
    const int tid = threadIdx.x;
    const int m0 = blockIdx.y * 64;
    const int n0 = blockIdx.x * 64;
    const int tx = tid & 15, ty = tid >> 4;
    const int lr = tid >> 2, lc = (tid & 3) * 4;

    float acc[4][4] = {};

    for (int k0 = 0; k0 < K; k0 += 16) {
        float4 a4 = *(const float4*)&A[(size_t)(m0 + lr) * K + k0 + lc];
        float4 b4 = *(const float4*)&W[(size_t)(n0 + lr) * K + k0 + lc];
        __syncthreads();
        As[lc + 0][lr] = a4.x; As[lc + 1][lr] = a4.y;
        As[lc + 2][lr] = a4.z; As[lc + 3][lr] = a4.w;
        Bs[lc + 0][lr] = b4.x; Bs[lc + 1][lr] = b4.y;
        Bs[lc + 2][lr] = b4.z; Bs[lc + 3][lr] = b4.w;
        __syncthreads();
#pragma unroll
        for (int kk = 0; kk < 16; kk++) {
            float4 av = *(const float4*)&As[kk][ty * 4];
            float4 bv = *(const float4*)&Bs[kk][tx * 4];
            float a[4] = {av.x, av.y, av.z, av.w};
            float b[4] = {bv.x, bv.y, bv.z, bv.w};
#pragma unroll
            for (int i = 0; i < 4; i++)
#pragma unroll
                for (int j = 0; j < 4; j++)
                    acc[i][j] = fmaf(a[i], b[j], acc[i][j]);
        }
    }

#pragma unroll
    for (int i = 0; i < 4; i++) {
        const int m = m0 + ty * 4 + i;
#pragma unroll
        for (int j = 0; j < 4; j++) {
            const int n = n0 + tx * 4 + j;
            const float v = acc[i][j] + bias[n];
            if (MODE == 0) {
                const int b = m / LL, l = m % LL;
                const int h = n / HD, d = n % HD;
                out[(((size_t)b * NH + h) * LL + l) * HD + d] = v;
            } else {
                out[(size_t)m * N + n] = v;
            }
        }
    }
}

// ---------------------------------------------------------------------------
// Attention with bit-emulated numpy-einsum f32 scores. One wave per q-row.
// Score emulation (numpy einsum_sumprod.c.src, baseline SSE3, no FMA):
//   4 SIMD lanes (element index mod 4), 4 iterations of vstep*4=16 elements,
//   block order 3,2,1,0: vacc = a0b0 + (a1b1 + (a2b2 + (a3b3 + vacc)))
//   [mul,add — NOT fma]; reduce: SSE3 hadd: (L0+L1)+(L2+L3); then /8 (exact).
// Selection: exact f32 U-th-largest (ties kept) via monotone-key search.
// ---------------------------------------------------------------------------
__global__ __launch_bounds__(256) void attn_np(
    const float* __restrict__ Qf, const float* __restrict__ Kf,
    const float* __restrict__ Vf, float* __restrict__ ctx, int U)
{
#pragma clang fp contract(off)
    const int tid  = threadIdx.x;
    const int lane = tid & 63;
    const int wv   = tid >> 6;
    const int l    = blockIdx.x * 4 + wv;
    const int h    = blockIdx.y;
    const int b    = blockIdx.z;
    const int bh   = b * NH + h;

    __shared__ float qs[4][HD];
    __shared__ float wls[4][64];
    __shared__ int   kls[4][64];

    qs[wv][lane] = Qf[((size_t)bh * LL + l) * HD + lane];
    __syncthreads();

    const float* __restrict__ Kb = Kf + (size_t)bh * LL * HD;
    const float4* __restrict__ qv4 = (const float4*)&qs[wv][0];

    float sreg[32];
    unsigned mv[32];
#pragma unroll 2
    for (int j = 0; j < 32; j++) {
        const float4* kr4 = (const float4*)(Kb + (size_t)(lane + 64 * j) * HD);
        float ax = 0.0f, ay = 0.0f, az = 0.0f, aw = 0.0f;
#pragma unroll
        for (int t = 0; t < 4; t++) {
#pragma unroll
            for (int sub = 3; sub >= 0; sub--) {
                const float4 kf = kr4[4 * t + sub];
                const float4 qf = qv4[4 * t + sub];
                ax = qf.x * kf.x + ax;   // mul+add, contract(off): no fma
                ay = qf.y * kf.y + ay;
                az = qf.z * kf.z + az;
                aw = qf.w * kf.w + aw;
            }
        }
        const float s = ((ax + ay) + (az + aw)) * 0.125f;
        sreg[j] = s;
        mv[j] = mono32(s);
    }

    // exact U-th-largest key (largest T with count(>=T) >= U)
    unsigned lo = 0u, hi = 0xFFFFFFFFu;
    while (lo < hi) {
        const unsigned span = hi - lo;
        const unsigned mid = lo + (span >> 1) + (span & 1u);
        int c = 0;
#pragma unroll
        for (int j = 0; j < 32; j++)
            c += (int)__popcll(__ballot(mv[j] >= mid));
        if (c >= U) lo = mid; else hi = mid - 1u;
    }

    // max over kept
    float mx = -INFINITY;
#pragma unroll
    for (int j = 0; j < 32; j++)
        if (mv[j] >= lo) mx = fmaxf(mx, sreg[j]);
#pragma unroll
    for (int off = 32; off > 0; off >>= 1)
        mx = fmaxf(mx, __shfl_xor(mx, off, 64));

    // compact kept (index order) into this wave's LDS slice
    const unsigned long long laneLT = (1ull << lane) - 1ull;
    int n = 0;
#pragma unroll
    for (int j = 0; j < 32; j++) {
        const bool p = (mv[j] >= lo);
        const unsigned long long ball = __ballot(p);
        if (p) {
            const int pos = n + (int)__popcll(ball & laneLT);
            if (pos < 64) {
                kls[wv][pos] = lane + 64 * j;
                wls[wv][pos] = expf(sreg[j] - mx);
            }
        }
        n += (int)__popcll(ball);
    }
    if (n > 64) n = 64;

    float dl = (lane < n) ? wls[wv][lane] : 0.0f;
#pragma unroll
    for (int off = 32; off > 0; off >>= 1) dl += __shfl_xor(dl, off, 64);
    const float rden = 1.0f / dl;

    const float* __restrict__ Vb = Vf + (size_t)bh * LL * HD;
    float acc = 0.0f;
    for (int c = 0; c < n; c++)
        acc = fmaf(wls[wv][c], Vb[(size_t)kls[wv][c] * HD + lane], acc);

    ctx[((size_t)b * LL + l) * DM + h * HD + lane] = acc * rden;
}

// ---------------------------------------------------------------------------
extern "C" void kernel_launch(void* const* d_in, const int* in_sizes, int n_in,
                              void* d_out, int out_size, void* d_ws, size_t ws_size,
                              hipStream_t stream)
{
    const float* x  = (const float*)d_in[0];
    const float* Wq = (const float*)d_in[1];
    const float* bq = (const float*)d_in[2];
    const float* Wk = (const float*)d_in[3];
    const float* bk = (const float*)d_in[4];
    const float* Wv = (const float*)d_in[5];
    const float* bv = (const float*)d_in[6];
    const float* Wo = (const float*)d_in[7];
    const float* bo = (const float*)d_in[8];
    float* out = (float*)d_out;

    const size_t E = (size_t)BB * NH * LL * HD;   // 4M elements
    float* Wt1 = (float*)d_ws;                    // 4 MB
    float* Wt2 = Wt1 + (size_t)DM * DM;           // 4 MB
    float* Qf  = Wt2 + (size_t)DM * DM;           // 16 MB
    float* Kf  = Qf + E;                          // 16 MB
    float* Vf  = Kf + E;                          // 16 MB
    float* ctx = Vf + E;                          // 16 MB   (72 MB total)

    int U = (int)(5.0 * log((double)LL));
    if (U > LL) U = LL;

    const int M = BB * LL;  // 4096
    dim3 blk(256);
    dim3 gT(DM / 32, DM / 32);
    dim3 gP(DM / 256, M / 8);
    dim3 g64(DM / 64, M / 64);

    hipLaunchKernelGGL(transpose1024, gT, blk, 0, stream, Wq, Wt1);
    hipLaunchKernelGGL(transpose1024, gT, blk, 0, stream, Wk, Wt2);
    hipLaunchKernelGGL(proj_emul, gP, blk, 0, stream, x, Wt1, bq, Qf);
    hipLaunchKernelGGL(proj_emul, gP, blk, 0, stream, x, Wt2, bk, Kf);
    hipLaunchKernelGGL((gemm_f32<0>), g64, blk, 0, stream, x, Wv, bv, Vf, M, DM, DM);
    hipLaunchKernelGGL(attn_np, dim3(LL / 4, NH, BB), blk, 0, stream, Qf, Kf, Vf, ctx, U);
    hipLaunchKernelGGL((gemm_f32<1>), g64, blk, 0, stream, ctx, Wo, bo, out, M, DM, DM);
}

// Round 7
// 3110.069 us; speedup vs baseline: 1.4327x; 1.4327x over previous
//
#include <hip/hip_runtime.h>
#include <math.h>

#define BB 2
#define LL 2048
#define DM 1024
#define NH 16
#define HD 64

__device__ __forceinline__ unsigned mono32(float f) {
    unsigned u = __float_as_uint(f);
    return (u & 0x80000000u) ? ~u : (u | 0x80000000u);
}
__device__ __forceinline__ float unmono32(unsigned m) {
    const unsigned u = (m & 0x80000000u) ? (m & 0x7FFFFFFFu) : ~m;
    return __uint_as_float(u);
}

// ---------------------------------------------------------------------------
// 1024x1024 transpose: out[k][n] = in[n][k]
// ---------------------------------------------------------------------------
__global__ __launch_bounds__(256) void transpose1024(
    const float* __restrict__ in, float* __restrict__ out)
{
    __shared__ float t[32][33];
    const int bx = blockIdx.x * 32, by = blockIdx.y * 32;
    const int tx = threadIdx.x & 31, ty = threadIdx.x >> 5;
    for (int r = ty; r < 32; r += 8)
        t[r][tx] = in[(size_t)(by + r) * DM + bx + tx];
    __syncthreads();
    for (int r = ty; r < 32; r += 8)
        out[(size_t)(bx + r) * DM + by + tx] = t[tx][r];
}

// ---------------------------------------------------------------------------
// Bit-emulated f32 projection (numpy -> OpenBLAS sgemm, Zen/Haswell):
// K-panels (384,320,320); serial ascending-k FMA chain per panel; C += panel;
// then +bias. Scatter to [B,H,L,D]. Wt is W transposed [k][n].  DO NOT TOUCH:
// bit-exactness of Q/K determines top-k selection (absmax margin is 6e-4).
// ---------------------------------------------------------------------------
__global__ __launch_bounds__(256) void proj_emul(
    const float* __restrict__ x, const float* __restrict__ Wt,
    const float* __restrict__ bias, float* __restrict__ outp)
{
    __shared__ float xs[8][DM];   // 32 KB
    const int tid = threadIdx.x;
    const int n   = blockIdx.x * 256 + tid;
    const int m0  = blockIdx.y * 8;

    for (int i = tid; i < 8 * 256; i += 256) {
        const int r = i >> 8, c4 = (i & 255) << 2;
        *(float4*)&xs[r][c4] = *(const float4*)&x[(size_t)(m0 + r) * DM + c4];
    }
    __syncthreads();

    const int kbound[4] = {0, 384, 704, 1024};   // OpenBLAS Zen panel splits

    float S[8] = {0, 0, 0, 0, 0, 0, 0, 0};
#pragma unroll
    for (int p = 0; p < 3; p++) {
        float P[8] = {0, 0, 0, 0, 0, 0, 0, 0};
        for (int k = kbound[p]; k < kbound[p + 1]; k++) {
            const float w = Wt[(size_t)k * DM + n];
#pragma unroll
            for (int m = 0; m < 8; m++) P[m] = fmaf(xs[m][k], w, P[m]);
        }
#pragma unroll
        for (int m = 0; m < 8; m++) S[m] += P[m];   // C += panel (in order)
    }

    const int h = n / HD, d = n % HD;
#pragma unroll
    for (int m = 0; m < 8; m++) {
        const int mm = m0 + m;
        const int b = mm / LL, l = mm % LL;
        outp[(((size_t)b * NH + h) * LL + l) * HD + d] = S[m] + bias[n];
    }
}

// ---------------------------------------------------------------------------
// f32 GEMM for V (MODE 0 scatter) and output projection (MODE 1).
// ---------------------------------------------------------------------------
template <int MODE>
__global__ __launch_bounds__(256) void gemm_f32(
    const float* __restrict__ A, const float* __restrict__ W,
    const float* __restrict__ bias, float* __restrict__ out,
    int M, int N, int K)
{
    __shared__ float As[16][64];
    __shared__ float Bs[16][64];
    const int tid = threadIdx.x;
    const int m0 = blockIdx.y * 64;
    const int n0 = blockIdx.x * 64;
    const int tx = tid & 15, ty = tid >> 4;
    const int lr = tid >> 2, lc = (tid & 3) * 4;

    float acc[4][4] = {};

    for (int k0 = 0; k0 < K; k0 += 16) {
        float4 a4 = *(const float4*)&A[(size_t)(m0 + lr) * K + k0 + lc];
        float4 b4 = *(const float4*)&W[(size_t)(n0 + lr) * K + k0 + lc];
        __syncthreads();
        As[lc + 0][lr] = a4.x; As[lc + 1][lr] = a4.y;
        As[lc + 2][lr] = a4.z; As[lc + 3][lr] = a4.w;
        Bs[lc + 0][lr] = b4.x; Bs[lc + 1][lr] = b4.y;
        Bs[lc + 2][lr] = b4.z; Bs[lc + 3][lr] = b4.w;
        __syncthreads();
#pragma unroll
        for (int kk = 0; kk < 16; kk++) {
            float4 av = *(const float4*)&As[kk][ty * 4];
            float4 bv = *(const float4*)&Bs[kk][tx * 4];
            float a[4] = {av.x, av.y, av.z, av.w};
            float b[4] = {bv.x, bv.y, bv.z, bv.w};
#pragma unroll
            for (int i = 0; i < 4; i++)
#pragma unroll
                for (int j = 0; j < 4; j++)
                    acc[i][j] = fmaf(a[i], b[j], acc[i][j]);
        }
    }

#pragma unroll
    for (int i = 0; i < 4; i++) {
        const int m = m0 + ty * 4 + i;
#pragma unroll
        for (int j = 0; j < 4; j++) {
            const int n = n0 + tx * 4 + j;
            const float v = acc[i][j] + bias[n];
            if (MODE == 0) {
                const int b = m / LL, l = m % LL;
                const int h = n / HD, d = n % HD;
                out[(((size_t)b * NH + h) * LL + l) * HD + d] = v;
            } else {
                out[(size_t)m * N + n] = v;
            }
        }
    }
}

// ---------------------------------------------------------------------------
// Attention v2: block = 8 q-rows of one (b,h), 256 threads = 4 waves.
//  - K staged in LDS as double-buffered 64-key tiles (coalesced, +4 pad)
//  - each wave computes scores for 2 rows; lane owns key = tile*64+lane;
//    bit-exact einsum-SSE3 chain (mul+add, contract off), scores -> LDS
//  - selection per row (wave): exact f32 U-th-largest via monotone-key
//    binary search on 32 regs; softmax + sparse PV identical to R6.
// ---------------------------------------------------------------------------
__global__ __launch_bounds__(256) void attn_np(
    const float* __restrict__ Qf, const float* __restrict__ Kf,
    const float* __restrict__ Vf, float* __restrict__ ctx, int U)
{
#pragma clang fp contract(off)
    const int tid  = threadIdx.x;
    const int lane = tid & 63;
    const int wv   = tid >> 6;
    const int l0   = blockIdx.x * 8;
    const int h    = blockIdx.y;
    const int b    = blockIdx.z;
    const int bh   = b * NH + h;

    __shared__ float sc[8][LL];        // 64 KB scores
    __shared__ float kt[2][64][68];    // 34 KB K tiles (+4 pad per row)
    __shared__ float qsh[8][64];       // 2 KB
    __shared__ float wls[8][64];       // 2 KB
    __shared__ int   kls[8][64];       // 2 KB

    const float* __restrict__ Kb = Kf + (size_t)bh * LL * HD;

    // stage q rows
    if (tid < 128) {
        const int r = tid >> 4, d4 = tid & 15;
        *(float4*)&qsh[r][d4 * 4] =
            *(const float4*)&Qf[((size_t)bh * LL + l0 + r) * HD + d4 * 4];
    }
    // stage K tile 0 (64 rows x 16 float4; 4 float4 per thread, coalesced)
#pragma unroll
    for (int i = 0; i < 4; i++) {
        const int idx = i * 256 + tid;
        *(float4*)&kt[0][idx >> 4][(idx & 15) * 4] =
            *(const float4*)&Kb[(size_t)(idx >> 4) * HD + (idx & 15) * 4];
    }
    __syncthreads();

    const int r0 = wv * 2, r1 = r0 + 1;

    for (int tile = 0; tile < 32; tile++) {
        const int buf = tile & 1;
        float4 pf0, pf1, pf2, pf3;
        if (tile < 31) {
            const float* src = Kb + (size_t)(tile + 1) * 64 * HD;
            pf0 = *(const float4*)&src[(size_t)((0 * 256 + tid) >> 4) * HD + ((0 * 256 + tid) & 15) * 4];
            pf1 = *(const float4*)&src[(size_t)((1 * 256 + tid) >> 4) * HD + ((1 * 256 + tid) & 15) * 4];
            pf2 = *(const float4*)&src[(size_t)((2 * 256 + tid) >> 4) * HD + ((2 * 256 + tid) & 15) * 4];
            pf3 = *(const float4*)&src[(size_t)((3 * 256 + tid) >> 4) * HD + ((3 * 256 + tid) & 15) * 4];
        }

        // scores for key = tile*64 + lane, rows r0 and r1 (bit-exact chain)
        float axA = 0, ayA = 0, azA = 0, awA = 0;
        float axB = 0, ayB = 0, azB = 0, awB = 0;
        const float* krow = &kt[buf][lane][0];
        const float* qA = &qsh[r0][0];
        const float* qB = &qsh[r1][0];
#pragma unroll
        for (int t = 0; t < 4; t++) {
#pragma unroll
            for (int sub = 3; sub >= 0; sub--) {
                const int d4 = 4 * t + sub;
                const float4 kf = *(const float4*)&krow[d4 * 4];
                const float4 qa = *(const float4*)&qA[d4 * 4];
                const float4 qb = *(const float4*)&qB[d4 * 4];
                axA = qa.x * kf.x + axA; ayA = qa.y * kf.y + ayA;
                azA = qa.z * kf.z + azA; awA = qa.w * kf.w + awA;
                axB = qb.x * kf.x + axB; ayB = qb.y * kf.y + ayB;
                azB = qb.z * kf.z + azB; awB = qb.w * kf.w + awB;
            }
        }
        sc[r0][tile * 64 + lane] = ((axA + ayA) + (azA + awA)) * 0.125f;
        sc[r1][tile * 64 + lane] = ((axB + ayB) + (azB + awB)) * 0.125f;

        __syncthreads();
        if (tile < 31) {
            *(float4*)&kt[buf ^ 1][(0 * 256 + tid) >> 4][((0 * 256 + tid) & 15) * 4] = pf0;
            *(float4*)&kt[buf ^ 1][(1 * 256 + tid) >> 4][((1 * 256 + tid) & 15) * 4] = pf1;
            *(float4*)&kt[buf ^ 1][(2 * 256 + tid) >> 4][((2 * 256 + tid) & 15) * 4] = pf2;
            *(float4*)&kt[buf ^ 1][(3 * 256 + tid) >> 4][((3 * 256 + tid) & 15) * 4] = pf3;
            __syncthreads();
        }
    }

    // ---- per-row selection + softmax + PV (wave handles rows r0, r1) ----
    const unsigned long long laneLT = (1ull << lane) - 1ull;
    const float* __restrict__ Vb = Vf + (size_t)bh * LL * HD;

#pragma unroll
    for (int rr8 = 0; rr8 < 2; rr8++) {
        const int rr = wv * 2 + rr8;

        unsigned mv[32];
#pragma unroll
        for (int j = 0; j < 32; j++) mv[j] = mono32(sc[rr][lane + 64 * j]);

        // exact U-th-largest key (largest T with count(>=T) >= U)
        unsigned lo = 0u, hi = 0xFFFFFFFFu;
        while (lo < hi) {
            const unsigned span = hi - lo;
            const unsigned mid = lo + (span >> 1) + (span & 1u);
            int c = 0;
#pragma unroll
            for (int j = 0; j < 32; j++)
                c += (int)__popcll(__ballot(mv[j] >= mid));
            if (c >= U) lo = mid; else hi = mid - 1u;
        }

        // max kept (reduce in key domain; lanes w/o kept contribute 0)
        unsigned mk = 0;
#pragma unroll
        for (int j = 0; j < 32; j++)
            if (mv[j] >= lo) mk = (mv[j] > mk) ? mv[j] : mk;
#pragma unroll
        for (int off = 32; off > 0; off >>= 1) {
            const unsigned o = __shfl_xor(mk, off, 64);
            mk = (o > mk) ? o : mk;
        }
        const float mx = unmono32(mk);

        // compact kept (index order)
        int n = 0;
#pragma unroll
        for (int j = 0; j < 32; j++) {
            const bool p = (mv[j] >= lo);
            const unsigned long long ball = __ballot(p);
            if (p) {
                const int pos = n + (int)__popcll(ball & laneLT);
                if (pos < 64) {
                    kls[rr][pos] = lane + 64 * j;
                    wls[rr][pos] = expf(unmono32(mv[j]) - mx);
                }
            }
            n += (int)__popcll(ball);
        }
        if (n > 64) n = 64;

        float dl = (lane < n) ? wls[rr][lane] : 0.0f;
#pragma unroll
        for (int off = 32; off > 0; off >>= 1) dl += __shfl_xor(dl, off, 64);
        const float rden = 1.0f / dl;

        float acc = 0.0f;
        for (int c = 0; c < n; c++)
            acc = fmaf(wls[rr][c], Vb[(size_t)kls[rr][c] * HD + lane], acc);

        ctx[((size_t)b * LL + l0 + rr) * DM + h * HD + lane] = acc * rden;
    }
}

// ---------------------------------------------------------------------------
extern "C" void kernel_launch(void* const* d_in, const int* in_sizes, int n_in,
                              void* d_out, int out_size, void* d_ws, size_t ws_size,
                              hipStream_t stream)
{
    const float* x  = (const float*)d_in[0];
    const float* Wq = (const float*)d_in[1];
    const float* bq = (const float*)d_in[2];
    const float* Wk = (const float*)d_in[3];
    const float* bk = (const float*)d_in[4];
    const float* Wv = (const float*)d_in[5];
    const float* bv = (const float*)d_in[6];
    const float* Wo = (const float*)d_in[7];
    const float* bo = (const float*)d_in[8];
    float* out = (float*)d_out;

    const size_t E = (size_t)BB * NH * LL * HD;   // 4M elements
    float* Wt1 = (float*)d_ws;                    // 4 MB
    float* Wt2 = Wt1 + (size_t)DM * DM;           // 4 MB
    float* Qf  = Wt2 + (size_t)DM * DM;           // 16 MB
    float* Kf  = Qf + E;                          // 16 MB
    float* Vf  = Kf + E;                          // 16 MB
    float* ctx = Vf + E;                          // 16 MB   (72 MB total)

    int U = (int)(5.0 * log((double)LL));
    if (U > LL) U = LL;

    const int M = BB * LL;  // 4096
    dim3 blk(256);
    dim3 gT(DM / 32, DM / 32);
    dim3 gP(DM / 256, M / 8);
    dim3 g64(DM / 64, M / 64);

    hipLaunchKernelGGL(transpose1024, gT, blk, 0, stream, Wq, Wt1);
    hipLaunchKernelGGL(transpose1024, gT, blk, 0, stream, Wk, Wt2);
    hipLaunchKernelGGL(proj_emul, gP, blk, 0, stream, x, Wt1, bq, Qf);
    hipLaunchKernelGGL(proj_emul, gP, blk, 0, stream, x, Wt2, bk, Kf);
    hipLaunchKernelGGL((gemm_f32<0>), g64, blk, 0, stream, x, Wv, bv, Vf, M, DM, DM);
    hipLaunchKernelGGL(attn_np, dim3(LL / 8, NH, BB), blk, 0, stream, Qf, Kf, Vf, ctx, U);
    hipLaunchKernelGGL((gemm_f32<1>), g64, blk, 0, stream, ctx, Wo, bo, out, M, DM, DM);
}